// Round 8
// baseline (6911.653 us; speedup 1.0000x reference)
//
#include <hip/hip_runtime.h>
#include <stdint.h>

// Problem dims (fixed)
#define B_  256
#define T_  1024
#define D_  128
#define H_  512
#define G4_ 2048            // 4*H
#define BT_ (B_ * T_)

// Persistent-LSTM partitioning: 16 batch groups x 8 col-WGs = 128 WGs
#define NG_  16             // batch groups (16 rows each)
#define NCW_ 8              // col-WGs per group (64 h-cols each)

typedef unsigned short u16;
typedef __attribute__((ext_vector_type(8))) short    bf16x8;  // 8 bf16 in 4 VGPRs
typedef __attribute__((ext_vector_type(8))) u16      u16x8;
typedef __attribute__((ext_vector_type(4))) float    f32x4;
typedef __attribute__((ext_vector_type(4))) uint32_t u32x4;

static __device__ __forceinline__ u16 f2bf(float f) {
  uint32_t u = __builtin_bit_cast(uint32_t, f);
  u += 0x7FFFu + ((u >> 16) & 1u);   // RNE
  return (u16)(u >> 16);
}

static __device__ __forceinline__ u16x8 pack8(float4 a, float4 b) {
  u16x8 p;
  p[0] = f2bf(a.x); p[1] = f2bf(a.y); p[2] = f2bf(a.z); p[3] = f2bf(a.w);
  p[4] = f2bf(b.x); p[5] = f2bf(b.y); p[6] = f2bf(b.z); p[7] = f2bf(b.w);
  return p;
}

static __device__ __forceinline__ float fast_sig(float x) {
  return 1.f / (1.f + __expf(-x));
}
static __device__ __forceinline__ float fast_tanh(float x) {
  return 1.f - 2.f / (__expf(2.f * x) + 1.f);
}

// ---------------------------------------------------------------------------
// prep: bf16 weight copies, bias sum, zero exchange buffer and out[:,0,:]
// ---------------------------------------------------------------------------
__global__ void prep_kernel(const float* __restrict__ Whh, const float* __restrict__ Wih,
                            const float* __restrict__ w1,  const float* __restrict__ w2,
                            const float* __restrict__ b_ih, const float* __restrict__ b_hh,
                            u16* __restrict__ Whh_bf, u16* __restrict__ Wih_bf,
                            u16* __restrict__ w1y_bf, u16* __restrict__ w2_bf,
                            float* __restrict__ w1s, float* __restrict__ bsum,
                            uint32_t* __restrict__ xch32, float* __restrict__ Yd) {
  const int idx = blockIdx.x * blockDim.x + threadIdx.x;
  if (idx < G4_ * H_) Whh_bf[idx] = f2bf(Whh[idx]);          // 1,048,576
  if (idx < G4_ * D_) Wih_bf[idx] = f2bf(Wih[idx]);          // 262,144
  if (idx < H_ * H_) {                                       // 262,144
    const int n = idx >> 9, k = idx & 511;
    w1y_bf[idx] = f2bf(w1[n * 513 + 1 + k]);                 // w1[:,1:]
    w2_bf[idx]  = f2bf(w2[idx]);
  }
  if (idx < H_)  w1s[idx]  = w1[idx * 513];                  // w1[:,0]
  if (idx < G4_) bsum[idx] = b_ih[idx] + b_hh[idx];
  if (idx < 2 * B_ * H_) xch32[idx] = 0;                     // 262,144 (tag 0)
  if (idx < B_ * H_) {                                       // 131,072
    const int b = idx >> 9, h = idx & 511;
    Yd[(size_t)b * T_ * H_ + h] = 0.f;                       // out[b,0,:] = h_0 = 0
  }
}

// x fp32 -> bf16 pre-conversion (33.5M elems; 16 per thread)
__global__ void xconv_kernel(const float* __restrict__ x, u16* __restrict__ xbf) {
  const size_t i = ((size_t)blockIdx.x * blockDim.x + threadIdx.x) * 16;
  const float4* s4 = (const float4*)(x + i);
  float4 a = s4[0], b = s4[1], c = s4[2], d = s4[3];
  *(u16x8*)(xbf + i)     = pack8(a, b);
  *(u16x8*)(xbf + i + 8) = pack8(c, d);
}

// ---------------------------------------------------------------------------
// Phase 1: persistent LSTM v6. Grid = 128 WGs x 256 thr (4 waves).
// WG (g,cw): rows [g*16,+16), h-cols [cw*64,+64). Each WAVE owns 16 h-cols
// and computes ALL 4 gates for them (4 acc frags sharing the same (row,col)
// lane mapping) -> LSTM update runs fully in-register, no gate exchange,
// no Gs LDS, publish immediately per wave.
// Weights: 80 frags (320 VGPR/lane), loaded once and PINNED via opaque
// asm "+v" per fragment (compiler cannot rematerialize an asm output from
// memory -> guaranteed register residency; R7's empty fence failed, VGPR=116).
// Exchange: self-validating tagged u32 words ((bf16(h)<<16)|step), u32
// stores sc0 sc1 -> MALL; consumers poll own 128 B with 8x coalesced
// dwordx4 sc0 sc1. Parity double-buffer; poll success at step s transitively
// proves peers finished reading parity (s&1) (R3 argument). Tags 1..1023;
// prep re-zeros each call (replay-safe).
// Barriers: 2/step (As-tile WAR): stage->bar->MFMA->update/publish->bar.
// ---------------------------------------------------------------------------
__launch_bounds__(256, 1)
__global__ void lstm_persist5(const u16* __restrict__ xbf,
                              const u16* __restrict__ Whh_bf,
                              const u16* __restrict__ Wih_bf,
                              const float* __restrict__ bsum,
                              float* __restrict__ Yd,
                              uint32_t* __restrict__ xch32) {
  __shared__ u16 As[16][648];         // 16 x 640 bf16 A-tile (+pad)

  const int tid  = threadIdx.x;
  const int lane = tid & 63;
  const int wv   = tid >> 6;          // wave 0..3
  const int bid  = blockIdx.x;
  const int g    = bid & 15;          // batch group (bid%8 fixed per g -> same XCD)
  const int cw   = bid >> 4;          // col-WG 0..7
  const int br0  = g * 16;

  const int cl = lane & 15;
  const int ko = (lane >> 4) * 8;
  const int jb = cw * 64 + wv * 16 + cl;   // global h col this lane owns

  // ---- persistent weight fragments: 4 gates x 20 kt (320 VGPR/lane) ----
  bf16x8 wf[4][20];
#pragma unroll
  for (int gt = 0; gt < 4; ++gt) {
    const size_t j0 = (size_t)(gt * H_ + jb);
#pragma unroll
    for (int kt = 0; kt < 16; ++kt)
      wf[gt][kt] = *(const bf16x8*)(Whh_bf + j0 * H_ + kt * 32 + ko);
#pragma unroll
    for (int kt = 0; kt < 4; ++kt)
      wf[gt][16 + kt] = *(const bf16x8*)(Wih_bf + j0 * D_ + kt * 32 + ko);
  }
  // PIN: opaque per-fragment asm output -> cannot be rematerialized from mem
#pragma unroll
  for (int gt = 0; gt < 4; ++gt)
#pragma unroll
    for (int kt = 0; kt < 20; ++kt)
      asm volatile("" : "+v"(wf[gt][kt]));

  // ---- per-lane cell state: 4 rows (row0..row0+3) x col jb ----
  const int row0 = (lane >> 4) * 4;
  float cst[4] = {0.f, 0.f, 0.f, 0.f};
  const float bi  = bsum[jb];
  const float bff = bsum[H_ + jb];
  const float bgg = bsum[2 * H_ + jb];
  const float boo = bsum[3 * H_ + jb];

  // staging maps
  const int prow = tid >> 4;          // poll row 0..15
  const int pcb  = (tid & 15) * 32;   // poll col base (h-value units)
  const u16* xrow = xbf + (size_t)(br0 + (tid >> 4)) * T_ * D_ + (tid & 15) * 8;

  for (int s = 0; s < T_ - 1; ++s) {
    // ---- x chunk (16 B/thread) — issued before poll, latency hidden ----
    const u16x8 xa = *(const u16x8*)(xrow + (size_t)s * D_);

    // ---- stage h-part (cols 0..511): coalesced tagged poll ----
    if (s == 0) {
      u16x8 z = {};
#pragma unroll
      for (int i = 0; i < 4; ++i) *(u16x8*)&As[prow][pcb + i * 8] = z;
    } else {
      const char* base = (const char*)(xch32 + (((size_t)(s & 1) * NG_ + g) << 13)) + tid * 128;
      const uint32_t want = (uint32_t)s;
      u32x4 r0, r1, r2, r3, r4, r5, r6, r7;
      bool ok;
      do {
        asm volatile(
          "global_load_dwordx4 %0, %8, off sc0 sc1\n\t"
          "global_load_dwordx4 %1, %8, off offset:16 sc0 sc1\n\t"
          "global_load_dwordx4 %2, %8, off offset:32 sc0 sc1\n\t"
          "global_load_dwordx4 %3, %8, off offset:48 sc0 sc1\n\t"
          "global_load_dwordx4 %4, %8, off offset:64 sc0 sc1\n\t"
          "global_load_dwordx4 %5, %8, off offset:80 sc0 sc1\n\t"
          "global_load_dwordx4 %6, %8, off offset:96 sc0 sc1\n\t"
          "global_load_dwordx4 %7, %8, off offset:112 sc0 sc1\n\t"
          "s_waitcnt vmcnt(0)"
          : "=&v"(r0), "=&v"(r1), "=&v"(r2), "=&v"(r3),
            "=&v"(r4), "=&v"(r5), "=&v"(r6), "=&v"(r7)
          : "v"(base) : "memory");
        ok = true;
#pragma unroll
        for (int i = 0; i < 4; ++i) {
          ok = ok && ((r0[i] & 0xFFFFu) == want) && ((r1[i] & 0xFFFFu) == want)
                  && ((r2[i] & 0xFFFFu) == want) && ((r3[i] & 0xFFFFu) == want)
                  && ((r4[i] & 0xFFFFu) == want) && ((r5[i] & 0xFFFFu) == want)
                  && ((r6[i] & 0xFFFFu) == want) && ((r7[i] & 0xFFFFu) == want);
        }
      } while (!ok);
      u16x8 d0, d1, d2, d3;
#pragma unroll
      for (int i = 0; i < 4; ++i) {
        d0[i] = (u16)(r0[i] >> 16); d0[4 + i] = (u16)(r1[i] >> 16);
        d1[i] = (u16)(r2[i] >> 16); d1[4 + i] = (u16)(r3[i] >> 16);
        d2[i] = (u16)(r4[i] >> 16); d2[4 + i] = (u16)(r5[i] >> 16);
        d3[i] = (u16)(r6[i] >> 16); d3[4 + i] = (u16)(r7[i] >> 16);
      }
      *(u16x8*)&As[prow][pcb]      = d0;
      *(u16x8*)&As[prow][pcb + 8]  = d1;
      *(u16x8*)&As[prow][pcb + 16] = d2;
      *(u16x8*)&As[prow][pcb + 24] = d3;
    }
    // ---- stage x-part (cols 512..639) ----
    *(u16x8*)&As[tid >> 4][512 + (tid & 15) * 8] = xa;
    __syncthreads();                  // barrier 1: stage -> MFMA

    // ---- MFMA: M=16, N=16 x 4 gates, K=640; 4 independent acc chains ----
    f32x4 a0 = {}, a1 = {}, a2 = {}, a3 = {};
#pragma unroll
    for (int kt = 0; kt < 20; ++kt) {
      bf16x8 a = *(const bf16x8*)&As[cl][kt * 32 + ko];
      a0 = __builtin_amdgcn_mfma_f32_16x16x32_bf16(a, wf[0][kt], a0, 0, 0, 0);
      a1 = __builtin_amdgcn_mfma_f32_16x16x32_bf16(a, wf[1][kt], a1, 0, 0, 0);
      a2 = __builtin_amdgcn_mfma_f32_16x16x32_bf16(a, wf[2][kt], a2, 0, 0, 0);
      a3 = __builtin_amdgcn_mfma_f32_16x16x32_bf16(a, wf[3][kt], a3, 0, 0, 0);
    }

    // ---- in-register LSTM update + immediate tagged publication ----
    {
      const uint32_t tag = (uint32_t)(s + 1);
      uint32_t* xdst = xch32 + (((size_t)((s + 1) & 1) * NG_ + g) << 13) + row0 * 512 + jb;
      float*    ydst = Yd + ((size_t)(br0 + row0) * T_ + (s + 1)) * H_ + jb;
#pragma unroll
      for (int r = 0; r < 4; ++r) {
        const float gi = a0[r] + bi;
        const float gf = a1[r] + bff;
        const float gg = a2[r] + bgg;
        const float go = a3[r] + boo;
        cst[r] = fast_sig(gf) * cst[r] + fast_sig(gi) * fast_tanh(gg);
        const float h = fast_sig(go) * fast_tanh(cst[r]);
        const uint32_t wd = ((uint32_t)f2bf(h) << 16) | tag;
        asm volatile("global_store_dword %0, %1, off sc0 sc1"
                     :: "v"(xdst + r * 512), "v"(wd) : "memory");
        ydst[(size_t)r * T_ * H_] = h;
      }
    }
    __syncthreads();                  // barrier 2: As WAR for next iteration
  }
}

// ---------------------------------------------------------------------------
// Phase 2 (fused, v2 — proven R5/R7): all 4 Euler steps; 64 rows x 512 cols
// per WG. 8 waves, 1x8: each wave M=64 (4 m-frags), N=64 (4 n-frags).
// Y fp32 in regs; A-tile bf16 in LDS; B weights loaded DIRECT from global
// (L2-resident) inside the cc-loop (reg double-buffer spilled in R6 — don't).
// ---------------------------------------------------------------------------
__launch_bounds__(512)
__global__ void ode_fused2(const float* __restrict__ tptr,
                           const u16* __restrict__ w1y,
                           const u16* __restrict__ w2v,
                           const float* __restrict__ b1,
                           const float* __restrict__ b2,
                           const float* __restrict__ w1s,
                           float* __restrict__ Yd) {
  __shared__ u16 At[64][520];

  const int tid  = threadIdx.x;
  const int lane = tid & 63;
  const int wv   = tid >> 6;          // 0..7
  const int n0w  = wv * 64;
  const size_t m0 = (size_t)blockIdx.x * 64;
  const int cl = lane & 15;
  const int rq = (lane >> 4) * 4;
  const int ko = (lane >> 4) * 8;

  float b1v[4], b2v[4], w1sv[4];
#pragma unroll
  for (int nf = 0; nf < 4; ++nf) {
    const int cg = n0w + nf * 16 + cl;
    b1v[nf] = b1[cg]; b2v[nf] = b2[cg]; w1sv[nf] = w1s[cg];
  }
  float tv[4][4];
#pragma unroll
  for (int mf = 0; mf < 4; ++mf)
#pragma unroll
    for (int r = 0; r < 4; ++r)
      tv[mf][r] = 0.25f * tptr[m0 + mf * 16 + rq + r];

  // load Y (fp32) into registers (C-frag layout, wave's 64-col band)
  f32x4 Y[4][4];
#pragma unroll
  for (int mf = 0; mf < 4; ++mf)
#pragma unroll
    for (int nf = 0; nf < 4; ++nf)
#pragma unroll
      for (int r = 0; r < 4; ++r)
        Y[mf][nf][r] = Yd[(m0 + mf * 16 + rq + r) * 512 + n0w + nf * 16 + cl];

#define WRITE_AT(EXPR)                                                        \
  do {                                                                        \
    _Pragma("unroll") for (int mf = 0; mf < 4; ++mf)                          \
    _Pragma("unroll") for (int nf = 0; nf < 4; ++nf)                          \
    _Pragma("unroll") for (int r = 0; r < 4; ++r)                             \
      At[mf * 16 + rq + r][n0w + nf * 16 + cl] = f2bf(EXPR);                  \
  } while (0)

#define GEMM_DIRECT(WPTR, ACC)                                                \
  do {                                                                        \
    _Pragma("unroll 2") for (int cc = 0; cc < 16; ++cc) {                     \
      bf16x8 bfv[4], af[4];                                                   \
      _Pragma("unroll") for (int nf = 0; nf < 4; ++nf)                        \
        bfv[nf] = *(const bf16x8*)((WPTR) + (size_t)(n0w + nf * 16 + cl) * 512\
                                   + cc * 32 + ko);                           \
      _Pragma("unroll") for (int mf = 0; mf < 4; ++mf)                        \
        af[mf] = *(const bf16x8*)&At[mf * 16 + cl][cc * 32 + ko];             \
      _Pragma("unroll") for (int mf = 0; mf < 4; ++mf)                        \
      _Pragma("unroll") for (int nf = 0; nf < 4; ++nf)                        \
        ACC[mf][nf] = __builtin_amdgcn_mfma_f32_16x16x32_bf16(                \
            af[mf], bfv[nf], ACC[mf][nf], 0, 0, 0);                           \
    }                                                                         \
  } while (0)

  WRITE_AT(Y[mf][nf][r]);
  __syncthreads();

#pragma unroll 1
  for (int k = 0; k < 4; ++k) {
    const float sk = 0.25f * k;
    // ---- GEMM1: G1 = tanh(A @ w1y^T + b1 + s*w1s) ----
    f32x4 acc[4][4] = {};
    GEMM_DIRECT(w1y, acc);
    __syncthreads();                  // At reads done
    WRITE_AT(fast_tanh(acc[mf][nf][r] + b1v[nf] + sk * w1sv[nf]));
    __syncthreads();
    // ---- GEMM2: Y += dt*t*(G1 @ w2^T + b2) ----
    f32x4 acc2[4][4] = {};
    GEMM_DIRECT(w2v, acc2);
    __syncthreads();                  // At reads done
#pragma unroll
    for (int mf = 0; mf < 4; ++mf)
#pragma unroll
      for (int nf = 0; nf < 4; ++nf)
#pragma unroll
        for (int r = 0; r < 4; ++r)
          Y[mf][nf][r] += tv[mf][r] * (acc2[mf][nf][r] + b2v[nf]);
    if (k < 3) {
      WRITE_AT(Y[mf][nf][r]);
      __syncthreads();
    }
  }
#undef GEMM_DIRECT
#undef WRITE_AT

  // write back Y (fp32)
#pragma unroll
  for (int mf = 0; mf < 4; ++mf)
#pragma unroll
    for (int nf = 0; nf < 4; ++nf)
#pragma unroll
      for (int r = 0; r < 4; ++r)
        Yd[(m0 + mf * 16 + rq + r) * 512 + n0w + nf * 16 + cl] = Y[mf][nf][r];
}

// ---------------------------------------------------------------------------
extern "C" void kernel_launch(void* const* d_in, const int* in_sizes, int n_in,
                              void* d_out, int out_size, void* d_ws, size_t ws_size,
                              hipStream_t stream) {
  const float* x    = (const float*)d_in[0];
  const float* t    = (const float*)d_in[1];
  const float* W_ih = (const float*)d_in[2];
  const float* W_hh = (const float*)d_in[3];
  const float* b_ih = (const float*)d_in[4];
  const float* b_hh = (const float*)d_in[5];
  const float* w1   = (const float*)d_in[6];
  const float* b1   = (const float*)d_in[7];
  const float* w2   = (const float*)d_in[8];
  const float* b2   = (const float*)d_in[9];
  float* Yd = (float*)d_out;   // (B,T,H) fp32; h history and ODE state

  char* ws = (char*)d_ws;
  size_t off = 0;
  auto alloc = [&](size_t bytes) {
    void* p = ws + off;
    off += (bytes + 255) & ~(size_t)255;
    return p;
  };
  u16*      Whh_bf = (u16*)alloc((size_t)G4_ * H_ * 2);          //   2 MB
  u16*      Wih_bf = (u16*)alloc((size_t)G4_ * D_ * 2);          // 512 KB
  u16*      w1y_bf = (u16*)alloc((size_t)H_ * H_ * 2);           // 512 KB
  u16*      w2_bf  = (u16*)alloc((size_t)H_ * H_ * 2);           // 512 KB
  float*    w1s    = (float*)alloc(H_ * 4);
  float*    bsum   = (float*)alloc(G4_ * 4);
  uint32_t* xch32  = (uint32_t*)alloc((size_t)2 * B_ * H_ * 4);  // 1 MB
  u16*      xbf    = (u16*)alloc((size_t)BT_ * D_ * 2);          // 64 MB

  prep_kernel<<<4096, 256, 0, stream>>>(W_hh, W_ih, w1, w2, b_ih, b_hh,
                                        Whh_bf, Wih_bf, w1y_bf, w2_bf, w1s, bsum, xch32, Yd);
  xconv_kernel<<<8192, 256, 0, stream>>>(x, xbf);

  // Phase 1: persistent LSTM (128 WGs x 256 thr; 1 WG/CU on half the CUs)
  lstm_persist5<<<dim3(NG_ * NCW_), 256, 0, stream>>>(xbf, Whh_bf, Wih_bf, bsum, Yd, xch32);

  // Phase 2: fused 4-step Euler ODE over all B*T rows
  ode_fused2<<<dim3(BT_ / 64), 512, 0, stream>>>(t, w1y_bf, w2_bf, b1, b2, w1s, Yd);
}